// Round 7
// baseline (45.502 us; speedup 1.0000x reference)
//
#include <hip/hip_runtime.h>
#include <hip/hip_bf16.h>

#define N_NODES 100000
#define CIN 64
#define COUT 64
#define KNBR 9
#define SENTINEL 1000000.0f
#define NTILES 6250    // N_NODES / 16
#define GWAVES 6250    // gather waves: 16 nodes each

typedef __attribute__((ext_vector_type(8))) short bf16x8;
typedef __attribute__((ext_vector_type(4))) float f32x4;
typedef __attribute__((ext_vector_type(2))) float f32x2;
typedef __attribute__((ext_vector_type(4))) float f32x4v;
typedef __attribute__((ext_vector_type(2))) unsigned u32x2;

__device__ inline unsigned short bfbits(float f) {
    __hip_bfloat16 h = __float2bfloat16(f);
    return __builtin_bit_cast(unsigned short, h);
}

// ---------------------------------------------------------------------------
// Kernel 1 (MFMA, grid-stride, x-prefetch pipelined):
//   C[j][n] = sum_c Wbig[j][c] * x[n][c]
//   row j <  64 of Wbig = W1-W2  -> A8[n][j]    = fp8(C + b[j])
//   row j >= 64 of Wbig = W2     -> B8[n][j-64] = fp8(C)
//   S[o] = SENTINEL * sum_c W2[o][c]  (fp32 side buffer)
// Wbig staged once per block in LDS (bf16, XOR-swizzled). x loads are
// NONTEMPORAL (read-once stream; keep L2 for the A8/B8 tables, which kernel 2
// re-reads). Next tile's x loads issue before current tile's MFMA/pack/store.
// ---------------------------------------------------------------------------
__global__ __launch_bounds__(256, 2) void edgeconv_precompute_mfma(
        const float* __restrict__ x,
        const float* __restrict__ W,
        const float* __restrict__ b,
        unsigned char* __restrict__ A8,
        unsigned char* __restrict__ B8,
        float* __restrict__ S)
{
    __shared__ unsigned short Wlds[128 * 64];   // 16 KiB

    const int tid  = threadIdx.x;
    const int lane = tid & 63;
    const int wave = tid >> 6;
    const int gwid = blockIdx.x * 4 + wave;
    const int totalWaves = gridDim.x * 4;

    const int lg = lane >> 4;   // 0..3
    const int lr = lane & 15;   // 0..15

    // ---- stage Wbig -> LDS (2 threads per row, 32 channels each)
    {
        const int row  = tid >> 1;          // 0..127
        const int c0   = (tid & 1) * 32;
        const int sw   = (row & 7) << 3;    // XOR swizzle in 8-ushort (16B) units
        unsigned short* dst = Wlds + row * 64;
        if (row < 64) {
            const float* p1 = W + (size_t)row * (2 * CIN) + c0;        // W1
            const float* p2 = p1 + CIN;                                // W2
#pragma unroll
            for (int g = 0; g < 4; ++g) {
                float4 u1a = *reinterpret_cast<const float4*>(p1 + g * 8);
                float4 u1b = *reinterpret_cast<const float4*>(p1 + g * 8 + 4);
                float4 u2a = *reinterpret_cast<const float4*>(p2 + g * 8);
                float4 u2b = *reinterpret_cast<const float4*>(p2 + g * 8 + 4);
                bf16x8 v;
                v[0] = (short)bfbits(u1a.x - u2a.x); v[1] = (short)bfbits(u1a.y - u2a.y);
                v[2] = (short)bfbits(u1a.z - u2a.z); v[3] = (short)bfbits(u1a.w - u2a.w);
                v[4] = (short)bfbits(u1b.x - u2b.x); v[5] = (short)bfbits(u1b.y - u2b.y);
                v[6] = (short)bfbits(u1b.z - u2b.z); v[7] = (short)bfbits(u1b.w - u2b.w);
                *reinterpret_cast<bf16x8*>(dst + ((c0 + g * 8) ^ sw)) = v;
            }
        } else {
            const float* p2 = W + (size_t)(row - 64) * (2 * CIN) + CIN + c0;  // W2
#pragma unroll
            for (int g = 0; g < 4; ++g) {
                float4 ua = *reinterpret_cast<const float4*>(p2 + g * 8);
                float4 ub = *reinterpret_cast<const float4*>(p2 + g * 8 + 4);
                bf16x8 v;
                v[0] = (short)bfbits(ua.x); v[1] = (short)bfbits(ua.y);
                v[2] = (short)bfbits(ua.z); v[3] = (short)bfbits(ua.w);
                v[4] = (short)bfbits(ub.x); v[5] = (short)bfbits(ub.y);
                v[6] = (short)bfbits(ub.z); v[7] = (short)bfbits(ub.w);
                *reinterpret_cast<bf16x8*>(dst + ((c0 + g * 8) ^ sw)) = v;
            }
        }
    }
    __syncthreads();

    // ---- per-wave W fragments from LDS (ds_read_b128, swizzle-matched)
    bf16x8 wf[8][2];
#pragma unroll
    for (int jt = 0; jt < 8; ++jt) {
        const int row = (jt < 4) ? (jt * 16 + lr) : (64 + (jt - 4) * 16 + lr);
        const int sw  = (row & 7) << 3;
#pragma unroll
        for (int kh = 0; kh < 2; ++kh) {
            const int c0 = (kh * 32 + lg * 8) ^ sw;
            wf[jt][kh] = *reinterpret_cast<const bf16x8*>(Wlds + row * 64 + c0);
        }
    }
    float bias[4][4];
#pragma unroll
    for (int jt = 0; jt < 4; ++jt)
#pragma unroll
        for (int r = 0; r < 4; ++r)
            bias[jt][r] = b[jt * 16 + lg * 4 + r];

    // ---- sentinel side-buffer (one wave, once): S[o] = SENTINEL * sum(W2[o])
    if (gwid == 0) {
        float s = 0.f;
        for (int c = 0; c < CIN; ++c) s += W[(size_t)lane * (2 * CIN) + CIN + c];
        S[lane] = SENTINEL * s;
    }

    // ---- grid-stride over 16-node tiles, next-tile x prefetch
    int t = gwid;
    if (t < NTILES) {
        f32x4v xu[4];
        {
            const float* bp = x + (size_t)(t * 16 + lr) * CIN + lg * 8;
            xu[0] = __builtin_nontemporal_load(reinterpret_cast<const f32x4v*>(bp));
            xu[1] = __builtin_nontemporal_load(reinterpret_cast<const f32x4v*>(bp + 4));
            xu[2] = __builtin_nontemporal_load(reinterpret_cast<const f32x4v*>(bp + 32));
            xu[3] = __builtin_nontemporal_load(reinterpret_cast<const f32x4v*>(bp + 36));
        }
        while (true) {
            const int tn = t + totalWaves;
            f32x4v xn[4];
            if (tn < NTILES) {
                const float* np = x + (size_t)(tn * 16 + lr) * CIN + lg * 8;
                xn[0] = __builtin_nontemporal_load(reinterpret_cast<const f32x4v*>(np));
                xn[1] = __builtin_nontemporal_load(reinterpret_cast<const f32x4v*>(np + 4));
                xn[2] = __builtin_nontemporal_load(reinterpret_cast<const f32x4v*>(np + 32));
                xn[3] = __builtin_nontemporal_load(reinterpret_cast<const f32x4v*>(np + 36));
            }

            bf16x8 xf[2];
#pragma unroll
            for (int kh = 0; kh < 2; ++kh) {
                f32x4v u0 = xu[kh * 2], u1 = xu[kh * 2 + 1];
                bf16x8 v;
                v[0] = (short)bfbits(u0.x); v[1] = (short)bfbits(u0.y);
                v[2] = (short)bfbits(u0.z); v[3] = (short)bfbits(u0.w);
                v[4] = (short)bfbits(u1.x); v[5] = (short)bfbits(u1.y);
                v[6] = (short)bfbits(u1.z); v[7] = (short)bfbits(u1.w);
                xf[kh] = v;
            }

            f32x4 acc[8];
#pragma unroll
            for (int jt = 0; jt < 8; ++jt) {
                f32x4 a = {0.f, 0.f, 0.f, 0.f};
                a = __builtin_amdgcn_mfma_f32_16x16x32_bf16(wf[jt][0], xf[0], a, 0, 0, 0);
                a = __builtin_amdgcn_mfma_f32_16x16x32_bf16(wf[jt][1], xf[1], a, 0, 0, 0);
                acc[jt] = a;
            }

            const int nrow = t * 16 + lr;
#pragma unroll
            for (int jt = 0; jt < 4; ++jt) {
                unsigned pk = __builtin_amdgcn_cvt_pk_fp8_f32(
                    acc[jt][0] + bias[jt][0], acc[jt][1] + bias[jt][1], 0, false);
                pk = __builtin_amdgcn_cvt_pk_fp8_f32(
                    acc[jt][2] + bias[jt][2], acc[jt][3] + bias[jt][3], (int)pk, true);
                *reinterpret_cast<unsigned*>(A8 + (size_t)nrow * COUT + jt * 16 + lg * 4) = pk;
            }
#pragma unroll
            for (int jt = 4; jt < 8; ++jt) {
                unsigned pk = __builtin_amdgcn_cvt_pk_fp8_f32(acc[jt][0], acc[jt][1], 0, false);
                pk = __builtin_amdgcn_cvt_pk_fp8_f32(acc[jt][2], acc[jt][3], (int)pk, true);
                *reinterpret_cast<unsigned*>(B8 + (size_t)nrow * COUT + (jt - 4) * 16 + lg * 4) = pk;
            }

            if (tn >= NTILES) break;
            xu[0] = xn[0]; xu[1] = xn[1]; xu[2] = xn[2]; xu[3] = xn[3];
            t = tn;
        }
    }
}

// ---------------------------------------------------------------------------
// Kernel 2: out[n][o] = relu(A8[n][o] + max_k hb_k[o])
// 16 nodes (2 batches) per wave; all 18 idx loads then all 18 B-row gathers
// issued before any decode (outstanding-load depth 2x vs R6). Sentinel index
// clamped on the hot path; rare lanes (~1e-5) recompute via select fixup.
// idx/A8 loads and out stores NONTEMPORAL so the 6.4MB B8 table stays in L2.
// ---------------------------------------------------------------------------
__global__ __launch_bounds__(256) void edgeconv_gather_max(
        const int* __restrict__ idx,
        const unsigned char* __restrict__ A8,
        const unsigned char* __restrict__ B8,
        const float* __restrict__ S,
        float* __restrict__ out)
{
    const int lane = threadIdx.x & 63;
    const int wave = threadIdx.x >> 6;
    const int wid = blockIdx.x * 4 + wave;
    if (wid >= GWAVES) return;
    const int sub = lane >> 3;                  // node within batch 0..7
    const int cl  = lane & 7;                   // 8 channels per lane
    const int n0 = wid * 16 + sub;
    const int n1 = n0 + 8;

    // ---- all 18 idx loads (nontemporal, read-once)
    const int* ip0 = idx + (size_t)n0 * KNBR;
    const int* ip1 = idx + (size_t)n1 * KNBR;
    int j0[KNBR], j1[KNBR];
#pragma unroll
    for (int k = 0; k < KNBR; ++k) j0[k] = __builtin_nontemporal_load(ip0 + k);
#pragma unroll
    for (int k = 0; k < KNBR; ++k) j1[k] = __builtin_nontemporal_load(ip1 + k);

    // ---- all 18 B-row gathers (clamped index; B8 cached)
    u32x2 bv0[KNBR], bv1[KNBR];
#pragma unroll
    for (int k = 0; k < KNBR; ++k) {
        const unsigned jc = min((unsigned)j0[k], (unsigned)(N_NODES - 1));
        bv0[k] = *reinterpret_cast<const u32x2*>(B8 + (size_t)jc * COUT + cl * 8);
    }
#pragma unroll
    for (int k = 0; k < KNBR; ++k) {
        const unsigned jc = min((unsigned)j1[k], (unsigned)(N_NODES - 1));
        bv1[k] = *reinterpret_cast<const u32x2*>(B8 + (size_t)jc * COUT + cl * 8);
    }

    // ---- A rows (nontemporal, read-once)
    u32x2 av0 = __builtin_nontemporal_load(
        reinterpret_cast<const u32x2*>(A8 + (size_t)n0 * COUT + cl * 8));
    u32x2 av1 = __builtin_nontemporal_load(
        reinterpret_cast<const u32x2*>(A8 + (size_t)n1 * COUT + cl * 8));

    // sentinel values for this lane's channels (tiny, L1-hot)
    float4 sv0 = *reinterpret_cast<const float4*>(S + cl * 8);
    float4 sv1 = *reinterpret_cast<const float4*>(S + cl * 8 + 4);

    // ---- hot-path reduction (assumes no sentinel)
    float m0[8], m1[8];
#pragma unroll
    for (int e = 0; e < 8; ++e) { m0[e] = -3.402823466e38f; m1[e] = -3.402823466e38f; }
    bool hs0 = false, hs1 = false;
#pragma unroll
    for (int k = 0; k < KNBR; ++k) {
        hs0 |= (j0[k] == N_NODES);
        f32x2 d0 = __builtin_amdgcn_cvt_pk_f32_fp8(bv0[k].x, false);
        f32x2 d1 = __builtin_amdgcn_cvt_pk_f32_fp8(bv0[k].x, true);
        f32x2 d2 = __builtin_amdgcn_cvt_pk_f32_fp8(bv0[k].y, false);
        f32x2 d3 = __builtin_amdgcn_cvt_pk_f32_fp8(bv0[k].y, true);
        m0[0] = fmaxf(m0[0], d0.x); m0[1] = fmaxf(m0[1], d0.y);
        m0[2] = fmaxf(m0[2], d1.x); m0[3] = fmaxf(m0[3], d1.y);
        m0[4] = fmaxf(m0[4], d2.x); m0[5] = fmaxf(m0[5], d2.y);
        m0[6] = fmaxf(m0[6], d3.x); m0[7] = fmaxf(m0[7], d3.y);
    }
#pragma unroll
    for (int k = 0; k < KNBR; ++k) {
        hs1 |= (j1[k] == N_NODES);
        f32x2 d0 = __builtin_amdgcn_cvt_pk_f32_fp8(bv1[k].x, false);
        f32x2 d1 = __builtin_amdgcn_cvt_pk_f32_fp8(bv1[k].x, true);
        f32x2 d2 = __builtin_amdgcn_cvt_pk_f32_fp8(bv1[k].y, false);
        f32x2 d3 = __builtin_amdgcn_cvt_pk_f32_fp8(bv1[k].y, true);
        m1[0] = fmaxf(m1[0], d0.x); m1[1] = fmaxf(m1[1], d0.y);
        m1[2] = fmaxf(m1[2], d1.x); m1[3] = fmaxf(m1[3], d1.y);
        m1[4] = fmaxf(m1[4], d2.x); m1[5] = fmaxf(m1[5], d2.y);
        m1[6] = fmaxf(m1[6], d3.x); m1[7] = fmaxf(m1[7], d3.y);
    }

    // ---- rare sentinel fixup: recompute with selects (exec-masked, ~1e-5)
    if (__builtin_expect(hs0, 0)) {
        const float sv[8] = {sv0.x, sv0.y, sv0.z, sv0.w, sv1.x, sv1.y, sv1.z, sv1.w};
#pragma unroll
        for (int e = 0; e < 8; ++e) m0[e] = -3.402823466e38f;
#pragma unroll
        for (int k = 0; k < KNBR; ++k) {
            const bool s = (j0[k] == N_NODES);
            f32x2 d0 = __builtin_amdgcn_cvt_pk_f32_fp8(bv0[k].x, false);
            f32x2 d1 = __builtin_amdgcn_cvt_pk_f32_fp8(bv0[k].x, true);
            f32x2 d2 = __builtin_amdgcn_cvt_pk_f32_fp8(bv0[k].y, false);
            f32x2 d3 = __builtin_amdgcn_cvt_pk_f32_fp8(bv0[k].y, true);
            m0[0] = fmaxf(m0[0], s ? sv[0] : d0.x); m0[1] = fmaxf(m0[1], s ? sv[1] : d0.y);
            m0[2] = fmaxf(m0[2], s ? sv[2] : d1.x); m0[3] = fmaxf(m0[3], s ? sv[3] : d1.y);
            m0[4] = fmaxf(m0[4], s ? sv[4] : d2.x); m0[5] = fmaxf(m0[5], s ? sv[5] : d2.y);
            m0[6] = fmaxf(m0[6], s ? sv[6] : d3.x); m0[7] = fmaxf(m0[7], s ? sv[7] : d3.y);
        }
    }
    if (__builtin_expect(hs1, 0)) {
        const float sv[8] = {sv0.x, sv0.y, sv0.z, sv0.w, sv1.x, sv1.y, sv1.z, sv1.w};
#pragma unroll
        for (int e = 0; e < 8; ++e) m1[e] = -3.402823466e38f;
#pragma unroll
        for (int k = 0; k < KNBR; ++k) {
            const bool s = (j1[k] == N_NODES);
            f32x2 d0 = __builtin_amdgcn_cvt_pk_f32_fp8(bv1[k].x, false);
            f32x2 d1 = __builtin_amdgcn_cvt_pk_f32_fp8(bv1[k].x, true);
            f32x2 d2 = __builtin_amdgcn_cvt_pk_f32_fp8(bv1[k].y, false);
            f32x2 d3 = __builtin_amdgcn_cvt_pk_f32_fp8(bv1[k].y, true);
            m1[0] = fmaxf(m1[0], s ? sv[0] : d0.x); m1[1] = fmaxf(m1[1], s ? sv[1] : d0.y);
            m1[2] = fmaxf(m1[2], s ? sv[2] : d1.x); m1[3] = fmaxf(m1[3], s ? sv[3] : d1.y);
            m1[4] = fmaxf(m1[4], s ? sv[4] : d2.x); m1[5] = fmaxf(m1[5], s ? sv[5] : d2.y);
            m1[6] = fmaxf(m1[6], s ? sv[6] : d3.x); m1[7] = fmaxf(m1[7], s ? sv[7] : d3.y);
        }
    }

    // ---- add A, relu, nontemporal stores
    {
        f32x2 a0 = __builtin_amdgcn_cvt_pk_f32_fp8(av0.x, false);
        f32x2 a1 = __builtin_amdgcn_cvt_pk_f32_fp8(av0.x, true);
        f32x2 a2 = __builtin_amdgcn_cvt_pk_f32_fp8(av0.y, false);
        f32x2 a3 = __builtin_amdgcn_cvt_pk_f32_fp8(av0.y, true);
        f32x4v o0 = {fmaxf(0.f, a0.x + m0[0]), fmaxf(0.f, a0.y + m0[1]),
                     fmaxf(0.f, a1.x + m0[2]), fmaxf(0.f, a1.y + m0[3])};
        f32x4v o1 = {fmaxf(0.f, a2.x + m0[4]), fmaxf(0.f, a2.y + m0[5]),
                     fmaxf(0.f, a3.x + m0[6]), fmaxf(0.f, a3.y + m0[7])};
        float* op = out + (size_t)n0 * COUT + cl * 8;
        __builtin_nontemporal_store(o0, reinterpret_cast<f32x4v*>(op));
        __builtin_nontemporal_store(o1, reinterpret_cast<f32x4v*>(op + 4));
    }
    {
        f32x2 a0 = __builtin_amdgcn_cvt_pk_f32_fp8(av1.x, false);
        f32x2 a1 = __builtin_amdgcn_cvt_pk_f32_fp8(av1.x, true);
        f32x2 a2 = __builtin_amdgcn_cvt_pk_f32_fp8(av1.y, false);
        f32x2 a3 = __builtin_amdgcn_cvt_pk_f32_fp8(av1.y, true);
        f32x4v o0 = {fmaxf(0.f, a0.x + m1[0]), fmaxf(0.f, a0.y + m1[1]),
                     fmaxf(0.f, a1.x + m1[2]), fmaxf(0.f, a1.y + m1[3])};
        f32x4v o1 = {fmaxf(0.f, a2.x + m1[4]), fmaxf(0.f, a2.y + m1[5]),
                     fmaxf(0.f, a3.x + m1[6]), fmaxf(0.f, a3.y + m1[7])};
        float* op = out + (size_t)n1 * COUT + cl * 8;
        __builtin_nontemporal_store(o0, reinterpret_cast<f32x4v*>(op));
        __builtin_nontemporal_store(o1, reinterpret_cast<f32x4v*>(op + 4));
    }
}

// ---------------------------------------------------------------------------
// Fallback: fully fused f32 (no workspace). Unused when ws is big enough.
// ---------------------------------------------------------------------------
__global__ void edgeconv_fused(const float* __restrict__ x,
                               const int* __restrict__ idx,
                               const float* __restrict__ W,
                               const float* __restrict__ b,
                               float* __restrict__ out)
{
    const int lane = threadIdx.x & 63;
    const int wave = threadIdx.x >> 6;
    const int wavesPerBlock = blockDim.x >> 6;
    const int totalWaves = gridDim.x * wavesPerBlock;
    const int waveId = blockIdx.x * wavesPerBlock + wave;
    const int o = lane;

    const float* wrow = W + (size_t)o * (2 * CIN);
    float wa[CIN], w2[CIN];
#pragma unroll
    for (int c = 0; c < CIN; c += 4) {
        float4 v1 = *reinterpret_cast<const float4*>(wrow + c);
        float4 v2 = *reinterpret_cast<const float4*>(wrow + CIN + c);
        w2[c + 0] = v2.x; w2[c + 1] = v2.y; w2[c + 2] = v2.z; w2[c + 3] = v2.w;
        wa[c + 0] = v1.x - v2.x; wa[c + 1] = v1.y - v2.y;
        wa[c + 2] = v1.z - v2.z; wa[c + 3] = v1.w - v2.w;
    }
    const float bias = b[o];
    float w2sum = 0.f;
#pragma unroll
    for (int c = 0; c < CIN; ++c) w2sum += w2[c];
    const float bsent = SENTINEL * w2sum;

    for (int n = waveId; n < N_NODES; n += totalWaves) {
        const int nu = __builtin_amdgcn_readfirstlane(n);
        const float* xr = x + (size_t)nu * CIN;
        float a = bias;
#pragma unroll
        for (int c = 0; c < CIN; c += 4) {
            float4 xv = *reinterpret_cast<const float4*>(xr + c);
            a = fmaf(xv.x, wa[c + 0], a);
            a = fmaf(xv.y, wa[c + 1], a);
            a = fmaf(xv.z, wa[c + 2], a);
            a = fmaf(xv.w, wa[c + 3], a);
        }
        const int* ip = idx + (size_t)nu * KNBR;
        float m = 0.f;
        for (int k = 0; k < KNBR; ++k) {
            const int jj = __builtin_amdgcn_readfirstlane(ip[k]);
            float hb;
            if (jj == N_NODES) {
                hb = bsent;
            } else {
                const float* xj = x + (size_t)jj * CIN;
                float acc = 0.f;
#pragma unroll
                for (int c = 0; c < CIN; c += 4) {
                    float4 xv = *reinterpret_cast<const float4*>(xj + c);
                    acc = fmaf(xv.x, w2[c + 0], acc);
                    acc = fmaf(xv.y, w2[c + 1], acc);
                    acc = fmaf(xv.z, w2[c + 2], acc);
                    acc = fmaf(xv.w, w2[c + 3], acc);
                }
                hb = acc;
            }
            m = fmaxf(m, a + hb);
        }
        out[(size_t)nu * COUT + o] = m;
    }
}

extern "C" void kernel_launch(void* const* d_in, const int* in_sizes, int n_in,
                              void* d_out, int out_size, void* d_ws, size_t ws_size,
                              hipStream_t stream) {
    const float* x    = (const float*)d_in[0];
    const int*   edge = (const int*)d_in[1];   // (2, N, K); we use edge[0] = first N*K
    const float* W    = (const float*)d_in[2];
    const float* b    = (const float*)d_in[3];
    float* out = (float*)d_out;

    const size_t bytesA = (size_t)N_NODES * COUT;              // fp8
    const size_t bytesB = (size_t)N_NODES * COUT;              // fp8
    const size_t needed = bytesA + bytesB + 64 * sizeof(float);

    if (ws_size >= needed) {
        unsigned char* A8 = (unsigned char*)d_ws;
        unsigned char* B8 = A8 + bytesA;
        float* S = (float*)(B8 + bytesB);
        edgeconv_precompute_mfma<<<782, 256, 0, stream>>>(x, W, b, A8, B8, S);
        const int gblocks = (GWAVES + 3) / 4;   // 4 waves/block, 16 nodes/wave
        edgeconv_gather_max<<<gblocks, 256, 0, stream>>>(edge, A8, B8, S, out);
    } else {
        edgeconv_fused<<<2048, 256, 0, stream>>>(x, edge, W, b, out);
    }
}

// Round 9
// 40.181 us; speedup vs baseline: 1.1324x; 1.1324x over previous
//
#include <hip/hip_runtime.h>
#include <hip/hip_bf16.h>

#define N_NODES 100000
#define CIN 64
#define COUT 64
#define KNBR 9
#define SENTINEL 1000000.0f
#define NTILES 6250   // N_NODES / 16

typedef __attribute__((ext_vector_type(8))) short bf16x8;
typedef __attribute__((ext_vector_type(4))) float f32x4;
typedef __attribute__((ext_vector_type(2))) float f32x2;
typedef __attribute__((ext_vector_type(2))) unsigned u32x2;

__device__ inline unsigned short bfbits(float f) {
    __hip_bfloat16 h = __float2bfloat16(f);
    return __builtin_bit_cast(unsigned short, h);
}

// ---------------------------------------------------------------------------
// Kernel 1 (MFMA, grid-stride) — byte-identical to R6 (known 41.9us config):
//   C[j][n] = sum_c Wbig[j][c] * x[n][c]
//   row j <  64 of Wbig = W1-W2  -> A8[n][j]    = fp8(C + b[j])
//   row j >= 64 of Wbig = W2     -> B8[n][j-64] = fp8(C)
//   S[o] = SENTINEL * sum_c W2[o][c]  (fp32 side buffer)
// ---------------------------------------------------------------------------
__global__ __launch_bounds__(256, 2) void edgeconv_precompute_mfma(
        const float* __restrict__ x,
        const float* __restrict__ W,
        const float* __restrict__ b,
        unsigned char* __restrict__ A8,
        unsigned char* __restrict__ B8,
        float* __restrict__ S)
{
    __shared__ unsigned short Wlds[128 * 64];   // 16 KiB

    const int tid  = threadIdx.x;
    const int lane = tid & 63;
    const int wave = tid >> 6;
    const int gwid = blockIdx.x * 4 + wave;
    const int totalWaves = gridDim.x * 4;

    const int lg = lane >> 4;   // 0..3
    const int lr = lane & 15;   // 0..15

    // ---- stage Wbig -> LDS (2 threads per row, 32 channels each)
    {
        const int row  = tid >> 1;          // 0..127
        const int c0   = (tid & 1) * 32;
        const int sw   = (row & 7) << 3;    // XOR swizzle in 8-ushort (16B) units
        unsigned short* dst = Wlds + row * 64;
        if (row < 64) {
            const float* p1 = W + (size_t)row * (2 * CIN) + c0;        // W1
            const float* p2 = p1 + CIN;                                // W2
#pragma unroll
            for (int g = 0; g < 4; ++g) {
                float4 u1a = *reinterpret_cast<const float4*>(p1 + g * 8);
                float4 u1b = *reinterpret_cast<const float4*>(p1 + g * 8 + 4);
                float4 u2a = *reinterpret_cast<const float4*>(p2 + g * 8);
                float4 u2b = *reinterpret_cast<const float4*>(p2 + g * 8 + 4);
                bf16x8 v;
                v[0] = (short)bfbits(u1a.x - u2a.x); v[1] = (short)bfbits(u1a.y - u2a.y);
                v[2] = (short)bfbits(u1a.z - u2a.z); v[3] = (short)bfbits(u1a.w - u2a.w);
                v[4] = (short)bfbits(u1b.x - u2b.x); v[5] = (short)bfbits(u1b.y - u2b.y);
                v[6] = (short)bfbits(u1b.z - u2b.z); v[7] = (short)bfbits(u1b.w - u2b.w);
                *reinterpret_cast<bf16x8*>(dst + ((c0 + g * 8) ^ sw)) = v;
            }
        } else {
            const float* p2 = W + (size_t)(row - 64) * (2 * CIN) + CIN + c0;  // W2
#pragma unroll
            for (int g = 0; g < 4; ++g) {
                float4 ua = *reinterpret_cast<const float4*>(p2 + g * 8);
                float4 ub = *reinterpret_cast<const float4*>(p2 + g * 8 + 4);
                bf16x8 v;
                v[0] = (short)bfbits(ua.x); v[1] = (short)bfbits(ua.y);
                v[2] = (short)bfbits(ua.z); v[3] = (short)bfbits(ua.w);
                v[4] = (short)bfbits(ub.x); v[5] = (short)bfbits(ub.y);
                v[6] = (short)bfbits(ub.z); v[7] = (short)bfbits(ub.w);
                *reinterpret_cast<bf16x8*>(dst + ((c0 + g * 8) ^ sw)) = v;
            }
        }
    }
    __syncthreads();

    // ---- per-wave W fragments from LDS (ds_read_b128, swizzle-matched)
    bf16x8 wf[8][2];
#pragma unroll
    for (int jt = 0; jt < 8; ++jt) {
        const int row = (jt < 4) ? (jt * 16 + lr) : (64 + (jt - 4) * 16 + lr);
        const int sw  = (row & 7) << 3;
#pragma unroll
        for (int kh = 0; kh < 2; ++kh) {
            const int c0 = (kh * 32 + lg * 8) ^ sw;
            wf[jt][kh] = *reinterpret_cast<const bf16x8*>(Wlds + row * 64 + c0);
        }
    }
    float bias[4][4];
#pragma unroll
    for (int jt = 0; jt < 4; ++jt)
#pragma unroll
        for (int r = 0; r < 4; ++r)
            bias[jt][r] = b[jt * 16 + lg * 4 + r];

    // ---- sentinel side-buffer (one wave, once): S[o] = SENTINEL * sum(W2[o])
    if (gwid == 0) {
        float s = 0.f;
        for (int c = 0; c < CIN; ++c) s += W[(size_t)lane * (2 * CIN) + CIN + c];
        S[lane] = SENTINEL * s;
    }

    // ---- grid-stride over 16-node tiles
    for (int t = gwid; t < NTILES; t += totalWaves) {
        const int n0 = t * 16;
        bf16x8 xf[2];
#pragma unroll
        for (int kh = 0; kh < 2; ++kh) {
            const float* p = x + (size_t)(n0 + lr) * CIN + kh * 32 + lg * 8;
            float4 u0 = *reinterpret_cast<const float4*>(p);
            float4 u1 = *reinterpret_cast<const float4*>(p + 4);
            bf16x8 v;
            v[0] = (short)bfbits(u0.x); v[1] = (short)bfbits(u0.y);
            v[2] = (short)bfbits(u0.z); v[3] = (short)bfbits(u0.w);
            v[4] = (short)bfbits(u1.x); v[5] = (short)bfbits(u1.y);
            v[6] = (short)bfbits(u1.z); v[7] = (short)bfbits(u1.w);
            xf[kh] = v;
        }

        f32x4 acc[8];
#pragma unroll
        for (int jt = 0; jt < 8; ++jt) {
            f32x4 a = {0.f, 0.f, 0.f, 0.f};
            a = __builtin_amdgcn_mfma_f32_16x16x32_bf16(wf[jt][0], xf[0], a, 0, 0, 0);
            a = __builtin_amdgcn_mfma_f32_16x16x32_bf16(wf[jt][1], xf[1], a, 0, 0, 0);
            acc[jt] = a;
        }

        // D: col(lr)=node, row(lg*4+r)=j -> lane owns channels jt*16+lg*4+{0..3}
        const int nrow = n0 + lr;
#pragma unroll
        for (int jt = 0; jt < 4; ++jt) {
            unsigned pk = __builtin_amdgcn_cvt_pk_fp8_f32(
                acc[jt][0] + bias[jt][0], acc[jt][1] + bias[jt][1], 0, false);
            pk = __builtin_amdgcn_cvt_pk_fp8_f32(
                acc[jt][2] + bias[jt][2], acc[jt][3] + bias[jt][3], (int)pk, true);
            *reinterpret_cast<unsigned*>(A8 + (size_t)nrow * COUT + jt * 16 + lg * 4) = pk;
        }
#pragma unroll
        for (int jt = 4; jt < 8; ++jt) {
            unsigned pk = __builtin_amdgcn_cvt_pk_fp8_f32(acc[jt][0], acc[jt][1], 0, false);
            pk = __builtin_amdgcn_cvt_pk_fp8_f32(acc[jt][2], acc[jt][3], (int)pk, true);
            *reinterpret_cast<unsigned*>(B8 + (size_t)nrow * COUT + (jt - 4) * 16 + lg * 4) = pk;
        }
    }
}

// ---------------------------------------------------------------------------
// Kernel 2: out[n][o] = relu(A8[n][o] + max_k hb_k[o])
// 8 nodes/wave (R6 TLP: 12500 waves) + branch-free clamp-hoisted gathers:
// all 9 idx loads, then all 9 clamped B-row gathers issued before any decode
// (R6 had the sentinel branch inside the k-loop -> serialized load issue).
// Rare sentinel fixup is one exec-masked recompute (~1e-5 of lanes).
// ---------------------------------------------------------------------------
__global__ __launch_bounds__(256) void edgeconv_gather_max(
        const int* __restrict__ idx,
        const unsigned char* __restrict__ A8,
        const unsigned char* __restrict__ B8,
        const float* __restrict__ S,
        float* __restrict__ out)
{
    const int lane = threadIdx.x & 63;
    const int wave = threadIdx.x >> 6;
    const int nw = blockIdx.x * 4 + wave;
    const int sub = lane >> 3;                  // node within wave 0..7
    const int cl  = lane & 7;                   // 8 channels per lane
    const int n = nw * 8 + sub;
    if (n >= N_NODES) return;

    // ---- all 9 idx loads
    const int* ip = idx + (size_t)n * KNBR;
    int j[KNBR];
#pragma unroll
    for (int k = 0; k < KNBR; ++k) j[k] = ip[k];

    // ---- all 9 B-row gathers, unconditional (clamped index)
    u32x2 bv[KNBR];
#pragma unroll
    for (int k = 0; k < KNBR; ++k) {
        const unsigned jc = min((unsigned)j[k], (unsigned)(N_NODES - 1));
        bv[k] = *reinterpret_cast<const u32x2*>(B8 + (size_t)jc * COUT + cl * 8);
    }
    u32x2 av = *reinterpret_cast<const u32x2*>(A8 + (size_t)n * COUT + cl * 8);

    // ---- hot-path reduction (assumes no sentinel)
    float m[8];
#pragma unroll
    for (int e = 0; e < 8; ++e) m[e] = -3.402823466e38f;
    bool hs = false;
#pragma unroll
    for (int k = 0; k < KNBR; ++k) {
        hs |= (j[k] == N_NODES);
        f32x2 d0 = __builtin_amdgcn_cvt_pk_f32_fp8(bv[k].x, false);
        f32x2 d1 = __builtin_amdgcn_cvt_pk_f32_fp8(bv[k].x, true);
        f32x2 d2 = __builtin_amdgcn_cvt_pk_f32_fp8(bv[k].y, false);
        f32x2 d3 = __builtin_amdgcn_cvt_pk_f32_fp8(bv[k].y, true);
        m[0] = fmaxf(m[0], d0.x); m[1] = fmaxf(m[1], d0.y);
        m[2] = fmaxf(m[2], d1.x); m[3] = fmaxf(m[3], d1.y);
        m[4] = fmaxf(m[4], d2.x); m[5] = fmaxf(m[5], d2.y);
        m[6] = fmaxf(m[6], d3.x); m[7] = fmaxf(m[7], d3.y);
    }

    // ---- rare sentinel fixup (exec-masked)
    if (__builtin_expect(hs, 0)) {
        float4 sv0 = *reinterpret_cast<const float4*>(S + cl * 8);
        float4 sv1 = *reinterpret_cast<const float4*>(S + cl * 8 + 4);
        const float sv[8] = {sv0.x, sv0.y, sv0.z, sv0.w, sv1.x, sv1.y, sv1.z, sv1.w};
#pragma unroll
        for (int e = 0; e < 8; ++e) m[e] = -3.402823466e38f;
#pragma unroll
        for (int k = 0; k < KNBR; ++k) {
            const bool s = (j[k] == N_NODES);
            f32x2 d0 = __builtin_amdgcn_cvt_pk_f32_fp8(bv[k].x, false);
            f32x2 d1 = __builtin_amdgcn_cvt_pk_f32_fp8(bv[k].x, true);
            f32x2 d2 = __builtin_amdgcn_cvt_pk_f32_fp8(bv[k].y, false);
            f32x2 d3 = __builtin_amdgcn_cvt_pk_f32_fp8(bv[k].y, true);
            m[0] = fmaxf(m[0], s ? sv[0] : d0.x); m[1] = fmaxf(m[1], s ? sv[1] : d0.y);
            m[2] = fmaxf(m[2], s ? sv[2] : d1.x); m[3] = fmaxf(m[3], s ? sv[3] : d1.y);
            m[4] = fmaxf(m[4], s ? sv[4] : d2.x); m[5] = fmaxf(m[5], s ? sv[5] : d2.y);
            m[6] = fmaxf(m[6], s ? sv[6] : d3.x); m[7] = fmaxf(m[7], s ? sv[7] : d3.y);
        }
    }

    // ---- add A, relu, store
    f32x2 a0 = __builtin_amdgcn_cvt_pk_f32_fp8(av.x, false);
    f32x2 a1 = __builtin_amdgcn_cvt_pk_f32_fp8(av.x, true);
    f32x2 a2 = __builtin_amdgcn_cvt_pk_f32_fp8(av.y, false);
    f32x2 a3 = __builtin_amdgcn_cvt_pk_f32_fp8(av.y, true);
    float4 o0, o1;
    o0.x = fmaxf(0.f, a0.x + m[0]); o0.y = fmaxf(0.f, a0.y + m[1]);
    o0.z = fmaxf(0.f, a1.x + m[2]); o0.w = fmaxf(0.f, a1.y + m[3]);
    o1.x = fmaxf(0.f, a2.x + m[4]); o1.y = fmaxf(0.f, a2.y + m[5]);
    o1.z = fmaxf(0.f, a3.x + m[6]); o1.w = fmaxf(0.f, a3.y + m[7]);
    float* op = out + (size_t)n * COUT + cl * 8;
    *reinterpret_cast<float4*>(op)     = o0;
    *reinterpret_cast<float4*>(op + 4) = o1;
}

// ---------------------------------------------------------------------------
// Fallback: fully fused f32 (no workspace). Unused when ws is big enough.
// ---------------------------------------------------------------------------
__global__ void edgeconv_fused(const float* __restrict__ x,
                               const int* __restrict__ idx,
                               const float* __restrict__ W,
                               const float* __restrict__ b,
                               float* __restrict__ out)
{
    const int lane = threadIdx.x & 63;
    const int wave = threadIdx.x >> 6;
    const int wavesPerBlock = blockDim.x >> 6;
    const int totalWaves = gridDim.x * wavesPerBlock;
    const int waveId = blockIdx.x * wavesPerBlock + wave;
    const int o = lane;

    const float* wrow = W + (size_t)o * (2 * CIN);
    float wa[CIN], w2[CIN];
#pragma unroll
    for (int c = 0; c < CIN; c += 4) {
        float4 v1 = *reinterpret_cast<const float4*>(wrow + c);
        float4 v2 = *reinterpret_cast<const float4*>(wrow + CIN + c);
        w2[c + 0] = v2.x; w2[c + 1] = v2.y; w2[c + 2] = v2.z; w2[c + 3] = v2.w;
        wa[c + 0] = v1.x - v2.x; wa[c + 1] = v1.y - v2.y;
        wa[c + 2] = v1.z - v2.z; wa[c + 3] = v1.w - v2.w;
    }
    const float bias = b[o];
    float w2sum = 0.f;
#pragma unroll
    for (int c = 0; c < CIN; ++c) w2sum += w2[c];
    const float bsent = SENTINEL * w2sum;

    for (int n = waveId; n < N_NODES; n += totalWaves) {
        const int nu = __builtin_amdgcn_readfirstlane(n);
        const float* xr = x + (size_t)nu * CIN;
        float a = bias;
#pragma unroll
        for (int c = 0; c < CIN; c += 4) {
            float4 xv = *reinterpret_cast<const float4*>(xr + c);
            a = fmaf(xv.x, wa[c + 0], a);
            a = fmaf(xv.y, wa[c + 1], a);
            a = fmaf(xv.z, wa[c + 2], a);
            a = fmaf(xv.w, wa[c + 3], a);
        }
        const int* ip = idx + (size_t)nu * KNBR;
        float m = 0.f;
        for (int k = 0; k < KNBR; ++k) {
            const int jj = __builtin_amdgcn_readfirstlane(ip[k]);
            float hb;
            if (jj == N_NODES) {
                hb = bsent;
            } else {
                const float* xj = x + (size_t)jj * CIN;
                float acc = 0.f;
#pragma unroll
                for (int c = 0; c < CIN; c += 4) {
                    float4 xv = *reinterpret_cast<const float4*>(xj + c);
                    acc = fmaf(xv.x, w2[c + 0], acc);
                    acc = fmaf(xv.y, w2[c + 1], acc);
                    acc = fmaf(xv.z, w2[c + 2], acc);
                    acc = fmaf(xv.w, w2[c + 3], acc);
                }
                hb = acc;
            }
            m = fmaxf(m, a + hb);
        }
        out[(size_t)nu * COUT + o] = m;
    }
}

extern "C" void kernel_launch(void* const* d_in, const int* in_sizes, int n_in,
                              void* d_out, int out_size, void* d_ws, size_t ws_size,
                              hipStream_t stream) {
    const float* x    = (const float*)d_in[0];
    const int*   edge = (const int*)d_in[1];   // (2, N, K); we use edge[0] = first N*K
    const float* W    = (const float*)d_in[2];
    const float* b    = (const float*)d_in[3];
    float* out = (float*)d_out;

    const size_t bytesA = (size_t)N_NODES * COUT;              // fp8
    const size_t bytesB = (size_t)N_NODES * COUT;              // fp8
    const size_t needed = bytesA + bytesB + 64 * sizeof(float);

    if (ws_size >= needed) {
        unsigned char* A8 = (unsigned char*)d_ws;
        unsigned char* B8 = A8 + bytesA;
        float* S = (float*)(B8 + bytesB);
        edgeconv_precompute_mfma<<<782, 256, 0, stream>>>(x, W, b, A8, B8, S);
        const int gblocks = (N_NODES + 31) / 32;   // 4 waves/block, 8 nodes/wave
        edgeconv_gather_max<<<gblocks, 256, 0, stream>>>(edge, A8, B8, S, out);
    } else {
        edgeconv_fused<<<2048, 256, 0, stream>>>(x, edge, W, b, out);
    }
}